// Round 14
// baseline (283.666 us; speedup 1.0000x reference)
//
#include <hip/hip_runtime.h>

#define N_USERS 100000
#define N_ITEMS 50000
#define N_NODES 150000
#define NNZ_EDGES 4000000
#define BATCH_SZ 16384
#define DIM 64
#define ALPHA 0.1f
#define BETA 0.9f          // 1 - ALPHA

#define BKT_SHIFT 10
#define BKT_ROWS  (1 << BKT_SHIFT)                        // 1024 rows per bucket
#define NBKT      ((N_NODES + BKT_ROWS - 1) >> BKT_SHIFT) // 147 (<= 256 CUs)
#define BKT_PAD   16               // bucketTotal stride (64B) -> own cache line
#define BIN_CHUNK 4096             // edges per producer block
#define N_BIN_BLOCKS ((NNZ_EDGES + BIN_CHUNK - 1) / BIN_CHUNK)  // 977
#define SEG_MAX   1024             // padded segment count (>= N_BIN_BLOCKS)
#define EDGES_PER_THREAD 30        // mean 27211/1024=26.6, +5 sigma < 28700

typedef float v2f __attribute__((ext_vector_type(2)));

// ---------- bf16 helpers (storage-only precision; accumulate in fp32) ------
__device__ __forceinline__ unsigned short gtn_f2bf(float f) {
    unsigned int u = __float_as_uint(f);
    u = u + 0x7FFFu + ((u >> 16) & 1u);      // round-to-nearest-even
    return (unsigned short)(u >> 16);
}
__device__ __forceinline__ unsigned int gtn_pack_bf16x2(float lo, float hi) {
    return ((unsigned int)gtn_f2bf(lo)) | (((unsigned int)gtn_f2bf(hi)) << 16);
}

// x0 (fp32 split inputs) -> x0b (bf16, concatenated). Coalesced, vectorized.
__global__ void gtn_cvt_kernel(const float* __restrict__ xu,
                               const float* __restrict__ xi,
                               unsigned short* __restrict__ x0b) {
    const int total4 = N_NODES * DIM / 4;
    const int boundary4 = N_USERS * DIM / 4;
    for (int i4 = blockIdx.x * blockDim.x + threadIdx.x; i4 < total4;
         i4 += gridDim.x * blockDim.x) {
        const float4 v = (i4 < boundary4)
            ? ((const float4*)xu)[i4]
            : ((const float4*)xi)[i4 - boundary4];
        ushort4 o;
        o.x = gtn_f2bf(v.x);
        o.y = gtn_f2bf(v.y);
        o.z = gtn_f2bf(v.z);
        o.w = gtn_f2bf(v.w);
        ((ushort4*)x0b)[i4] = o;
    }
}

// ---------- CSR build: block-major LDS-sorted binning (unchanged R12) ------
__global__ void gtn_bin_sort_kernel(const int* __restrict__ row,
                                    const int* __restrict__ col,
                                    const float* __restrict__ w,
                                    int2* __restrict__ binned,      // block-major
                                    int2* __restrict__ blkSeg,      // [bkt][blk]
                                    int* __restrict__ bucketTotal) { // stride BKT_PAD
    __shared__ int hist[NBKT];
    __shared__ int scanb[512];
    __shared__ int cursor[NBKT];
    __shared__ int2 stage[BIN_CHUNK];                // 32 KB
    const int blk = blockIdx.x;
    const int t = threadIdx.x;                       // blockDim == 512
    const int chunkStart = blk * BIN_CHUNK;
    const int chunkN = min(BIN_CHUNK, NNZ_EDGES - chunkStart);

    for (int b = t; b < NBKT; b += 512) hist[b] = 0;
    __syncthreads();

    int rloc[BIN_CHUNK / 512];                       // 8 rows in registers
#pragma unroll
    for (int k = 0; k < BIN_CHUNK / 512; ++k) {
        const int i = t + k * 512;
        int r = -1;
        if (i < chunkN) {
            r = row[chunkStart + i];
            atomicAdd(&hist[r >> BKT_SHIFT], 1);
        }
        rloc[k] = r;
    }
    __syncthreads();

    const int hv = (t < NBKT) ? hist[t] : 0;
    scanb[t] = hv;
    __syncthreads();
    for (int off = 1; off < 512; off <<= 1) {
        const int tv = (t >= off) ? scanb[t - off] : 0;
        __syncthreads();
        scanb[t] += tv;
        __syncthreads();
    }
    if (t < NBKT) {
        const int exc = scanb[t] - hv;
        cursor[t] = exc;
        blkSeg[(size_t)t * N_BIN_BLOCKS + blk] = make_int2(exc, hv);
        if (hv) atomicAdd(&bucketTotal[t * BKT_PAD], hv);  // non-returning
    }
    __syncthreads();

#pragma unroll
    for (int k = 0; k < BIN_CHUNK / 512; ++k) {
        const int i = t + k * 512;
        if (i < chunkN) {
            const int r = rloc[k];
            const int b = r >> BKT_SHIFT;
            const int pos = atomicAdd(&cursor[b], 1);
            stage[pos] = make_int2(col[chunkStart + i] | ((r & (BKT_ROWS - 1)) << 18),
                                   __float_as_int(w[chunkStart + i]));
        }
    }
    __syncthreads();

    int2* dst = binned + (size_t)chunkStart;
#pragma unroll
    for (int k = 0; k < BIN_CHUNK / 512; ++k) {
        const int i = t + k * 512;
        if (i < chunkN) dst[i] = stage[i];
    }
}

// Tiny exclusive scan of the 147 bucket totals -> bktBase. One block.
__global__ void gtn_bktbase_kernel(const int* __restrict__ bucketTotal,
                                   int* __restrict__ bktBase) {
    __shared__ int s[512];
    const int t = threadIdx.x;
    const int v = (t < NBKT) ? bucketTotal[t * BKT_PAD] : 0;
    s[t] = v;
    __syncthreads();
    for (int off = 1; off < 512; off <<= 1) {
        const int tv = (t >= off) ? s[t - off] : 0;
        __syncthreads();
        s[t] += tv;
        __syncthreads();
    }
    if (t < NBKT) bktBase[t] = s[t] - v;
}

// Consumer (unchanged R12): compaction by binary search, edges in registers.
__global__ void gtn_bucket_csr_kernel(const int2* __restrict__ binned,
                                      const int2* __restrict__ blkSeg,
                                      const int* __restrict__ bktBase,
                                      int* __restrict__ rowPtr,
                                      int* __restrict__ cnt,
                                      int2* __restrict__ colw) {
    __shared__ int incl[SEG_MAX];
    __shared__ int segIdx[SEG_MAX];
    __shared__ int hist[BKT_ROWS];
    __shared__ int scan[BKT_ROWS];
    __shared__ int cursor[BKT_ROWS];
    const int b = blockIdx.x;
    const int t = threadIdx.x;         // blockDim == 1024

    int2 seg = make_int2(0, 0);
    if (t < N_BIN_BLOCKS) seg = blkSeg[(size_t)b * N_BIN_BLOCKS + t];
    segIdx[t] = t * BIN_CHUNK + seg.x;
    incl[t] = seg.y;
    hist[t] = 0;
    __syncthreads();
    for (int off = 1; off < SEG_MAX; off <<= 1) {
        const int tv = (t >= off) ? incl[t - off] : 0;
        __syncthreads();
        incl[t] += tv;
        __syncthreads();
    }
    const int n = incl[SEG_MAX - 1];

    int2 e[EDGES_PER_THREAD];
#pragma unroll
    for (int k = 0; k < EDGES_PER_THREAD; ++k) {
        const int i = t + k * 1024;
        if (i < n) {
            int s = 0;
#pragma unroll
            for (int st = 512; st > 0; st >>= 1) {
                const int c = s + st;
                if (c <= SEG_MAX && incl[c - 1] <= i) s = c;
            }
            const int base = s ? incl[s - 1] : 0;
            e[k] = binned[(size_t)segIdx[s] + (i - base)];
            atomicAdd(&hist[((unsigned)e[k].x) >> 18], 1);
        }
    }
    __syncthreads();

    const int v = hist[t];
    scan[t] = v;
    __syncthreads();
    for (int off = 1; off < BKT_ROWS; off <<= 1) {
        const int tv = (t >= off) ? scan[t - off] : 0;
        __syncthreads();
        scan[t] += tv;
        __syncthreads();
    }
    const int g = (b << BKT_SHIFT) + t;
    const int pos0 = bktBase[b] + scan[t] - v;
    if (g < N_NODES) { cnt[g] = v; rowPtr[g] = pos0; }
    cursor[t] = pos0;
    __syncthreads();

#pragma unroll
    for (int k = 0; k < EDGES_PER_THREAD; ++k) {
        const int i = t + k * 1024;
        if (i < n) {
            const int inrow = ((unsigned)e[k].x) >> 18;
            const int pos = atomicAdd(&cursor[inrow], 1);
            colw[pos] = make_int2(e[k].x & 0x3FFFF, e[k].y);
        }
    }
}

// ---------- gather: ONE 8-lane GROUP OWNS ONE NODE ----------
// lane = grp*8 + sub. Group grp walks its own node's edge list; lane holds
// dims [8*sub,8*sub+8) as 4 packed float2 accumulators (v_pk_fma_f32).
// No cross-group reduce. Loop runs to wave-max(n); short groups pad with
// e=(0,0) -> c=0,w=0 -> row-0 load (L1-hit) + FMA with 0.
__device__ __forceinline__ void gtn_gather_grp(
        int start, int n, int nmax, int sub, int grp,
        const unsigned short* __restrict__ x,
        const int2* __restrict__ colw, v2f acc[4]) {
    for (int base = 0; base < nmax; base += 8) {
        int2 e = make_int2(0, 0);
        if (base + sub < n) e = colw[start + base + sub];   // 64B per group
#pragma unroll
        for (int k = 0; k < 8; k += 4) {
            uint4 xv[4];
            float wv[4];
#pragma unroll
            for (int q = 0; q < 4; ++q) {
                const int srcl = (grp << 3) + k + q;
                const int c = __shfl(e.x, srcl, 64);
                wv[q] = __int_as_float(__shfl(e.y, srcl, 64));
                xv[q] = *(const uint4*)(x + ((size_t)c << 6) + (sub << 3));
            }
#pragma unroll
            for (int q = 0; q < 4; ++q) {
                const v2f w2 = {wv[q], wv[q]};
                v2f p0 = {__uint_as_float(xv[q].x << 16),
                          __uint_as_float(xv[q].x & 0xFFFF0000u)};
                v2f p1 = {__uint_as_float(xv[q].y << 16),
                          __uint_as_float(xv[q].y & 0xFFFF0000u)};
                v2f p2 = {__uint_as_float(xv[q].z << 16),
                          __uint_as_float(xv[q].z & 0xFFFF0000u)};
                v2f p3 = {__uint_as_float(xv[q].w << 16),
                          __uint_as_float(xv[q].w & 0xFFFF0000u)};
                acc[0] += w2 * p0;
                acc[1] += w2 * p1;
                acc[2] += w2 * p2;
                acc[3] += w2 * p3;
            }
        }
    }
}

__device__ __forceinline__ int gtn_wave_max(int v) {
    v = max(v, __shfl_xor(v, 8, 64));
    v = max(v, __shfl_xor(v, 16, 64));
    v = max(v, __shfl_xor(v, 32, 64));
    return v;
}

// Layer: wave handles 8 consecutive nodes (one per group). All lanes active
// in epilogue: wave writes 8 consecutive bf16 rows = 1KB contiguous.
__global__ void gtn_layer_kernel(const unsigned short* __restrict__ x,
                                 const float* __restrict__ x0u,
                                 const float* __restrict__ x0i,
                                 const int* __restrict__ rowPtr,
                                 const int* __restrict__ cnt,
                                 const int2* __restrict__ colw,
                                 unsigned short* __restrict__ out) {
    const int lane = threadIdx.x & 63;
    const int sub = lane & 7;
    const int grp = lane >> 3;
    const int wid = (blockIdx.x * blockDim.x + threadIdx.x) >> 6;
    const int node = wid * 8 + grp;
    if (wid * 8 >= N_NODES) return;
    const bool valid = node < N_NODES;
    const int nv = valid ? node : 0;
    const int start = rowPtr[nv];
    const int n = valid ? cnt[nv] : 0;
    const int nmax = gtn_wave_max(n);

    v2f acc[4] = {{0.f, 0.f}, {0.f, 0.f}, {0.f, 0.f}, {0.f, 0.f}};
    gtn_gather_grp(start, n, nmax, sub, grp, x, colw, acc);

    if (valid) {
        const float* x0p = (node < N_USERS)
            ? x0u + (size_t)node * DIM + (sub << 3)
            : x0i + (size_t)(node - N_USERS) * DIM + (sub << 3);
        const float4 a = ((const float4*)x0p)[0];
        const float4 c = ((const float4*)x0p)[1];
        uint4 o;
        o.x = gtn_pack_bf16x2(ALPHA * a.x + BETA * acc[0].x,
                              ALPHA * a.y + BETA * acc[0].y);
        o.y = gtn_pack_bf16x2(ALPHA * a.z + BETA * acc[1].x,
                              ALPHA * a.w + BETA * acc[1].y);
        o.z = gtn_pack_bf16x2(ALPHA * c.x + BETA * acc[2].x,
                              ALPHA * c.y + BETA * acc[2].y);
        o.w = gtn_pack_bf16x2(ALPHA * c.z + BETA * acc[3].x,
                              ALPHA * c.w + BETA * acc[3].y);
        *(uint4*)(out + (size_t)node * DIM + (sub << 3)) = o;
    }
}

// Fused layer-3 + dot: wave handles 4 batch elements; groups 0-3 gather the
// user nodes, groups 4-7 the item nodes; cross-half shfl_xor(32) for the dot.
__global__ void gtn_l3_dot_kernel(const unsigned short* __restrict__ x,
                                  const float* __restrict__ x0u,
                                  const float* __restrict__ x0i,
                                  const int* __restrict__ rowPtr,
                                  const int* __restrict__ cnt,
                                  const int2* __restrict__ colw,
                                  const int* __restrict__ users,
                                  const int* __restrict__ items,
                                  float* __restrict__ out) {
    const int lane = threadIdx.x & 63;
    const int sub = lane & 7;
    const int grp = lane >> 3;
    const int wid = (blockIdx.x * blockDim.x + threadIdx.x) >> 6;
    const int b = wid * 4 + (grp & 3);
    if (wid * 4 >= BATCH_SZ) return;
    const bool valid = b < BATCH_SZ;
    const int bv = valid ? b : 0;
    const bool isItem = grp >= 4;
    const int node = isItem ? items[bv] + N_USERS : users[bv];
    const int start = rowPtr[node];
    const int n = valid ? cnt[node] : 0;
    const int nmax = gtn_wave_max(n);

    v2f acc[4] = {{0.f, 0.f}, {0.f, 0.f}, {0.f, 0.f}, {0.f, 0.f}};
    gtn_gather_grp(start, n, nmax, sub, grp, x, colw, acc);

    // v = ALPHA*x0 + BETA*acc (8 dims per lane)
    const float* x0p = isItem
        ? x0i + (size_t)(node - N_USERS) * DIM + (sub << 3)
        : x0u + (size_t)node * DIM + (sub << 3);
    const float4 a = ((const float4*)x0p)[0];
    const float4 c = ((const float4*)x0p)[1];
    float v[8];
    v[0] = ALPHA * a.x + BETA * acc[0].x;
    v[1] = ALPHA * a.y + BETA * acc[0].y;
    v[2] = ALPHA * a.z + BETA * acc[1].x;
    v[3] = ALPHA * a.w + BETA * acc[1].y;
    v[4] = ALPHA * c.x + BETA * acc[2].x;
    v[5] = ALPHA * c.y + BETA * acc[2].y;
    v[6] = ALPHA * c.z + BETA * acc[3].x;
    v[7] = ALPHA * c.w + BETA * acc[3].y;

    float p = 0.f;
#pragma unroll
    for (int d = 0; d < 8; ++d) {
        const float other = __shfl_xor(v[d], 32, 64);   // partner half
        p = fmaf(v[d], other, p);
    }
    // reduce over the 8 subs of the group
    p += __shfl_xor(p, 1, 64);
    p += __shfl_xor(p, 2, 64);
    p += __shfl_xor(p, 4, 64);
    if (valid && !isItem && sub == 0) out[b] = p;
}

extern "C" void kernel_launch(void* const* d_in, const int* in_sizes, int n_in,
                              void* d_out, int out_size, void* d_ws, size_t ws_size,
                              hipStream_t stream) {
    const float* user_emb  = (const float*)d_in[0];
    const float* item_emb  = (const float*)d_in[1];
    const float* edge_vals = (const float*)d_in[2];
    const int*   row       = (const int*)d_in[3];
    const int*   col       = (const int*)d_in[4];
    const int*   users     = (const int*)d_in[5];
    const int*   items     = (const int*)d_in[6];
    float* out = (float*)d_out;

    // workspace layout (~124 MB)
    char* p = (char*)d_ws;
    unsigned short* x0b  = (unsigned short*)p; p += (size_t)N_NODES * DIM * 2; // 19.2 MB
    unsigned short* bufA = (unsigned short*)p; p += (size_t)N_NODES * DIM * 2; // 19.2 MB
    unsigned short* bufB = (unsigned short*)p; p += (size_t)N_NODES * DIM * 2; // 19.2 MB
    int2*  colw        = (int2*)p; p += (size_t)NNZ_EDGES * sizeof(int2);      // 32 MB
    int2*  binned      = (int2*)p; p += (size_t)NNZ_EDGES * sizeof(int2);      // 32 MB
    int2*  blkSeg      = (int2*)p; p += (size_t)NBKT * N_BIN_BLOCKS * sizeof(int2); // 1.15 MB
    int*   bucketTotal = (int*)p;  p += (size_t)NBKT * BKT_PAD * sizeof(int);  // 9.2 KB
    int*   bktBase     = (int*)p;  p += 512 * sizeof(int);
    int*   cnt         = (int*)p;  p += (size_t)N_NODES * sizeof(int);
    int*   rowPtr      = (int*)p;  p += (size_t)N_NODES * sizeof(int);

    const dim3 blk(256);

    // ---- CSR build (block-major LDS-sorted binning) + x0 bf16 conversion ----
    hipMemsetAsync(bucketTotal, 0, (size_t)NBKT * BKT_PAD * sizeof(int), stream);
    gtn_bin_sort_kernel<<<dim3(N_BIN_BLOCKS), dim3(512), 0, stream>>>(
        row, col, edge_vals, binned, blkSeg, bucketTotal);
    gtn_cvt_kernel<<<dim3(2048), blk, 0, stream>>>(user_emb, item_emb, x0b);
    gtn_bktbase_kernel<<<dim3(1), dim3(512), 0, stream>>>(bucketTotal, bktBase);
    gtn_bucket_csr_kernel<<<dim3(NBKT), dim3(1024), 0, stream>>>(
        binned, blkSeg, bktBase, rowPtr, cnt, colw);

    // ---- layers: wave = 8 nodes (one per 8-lane group) ----
    const dim3 layerGrid((N_NODES / 8 + 3) / 4);        // 4688 blocks (4 waves ea)
    gtn_layer_kernel<<<layerGrid, blk, 0, stream>>>(
        x0b, user_emb, item_emb, rowPtr, cnt, colw, bufA);
    gtn_layer_kernel<<<layerGrid, blk, 0, stream>>>(
        bufA, user_emb, item_emb, rowPtr, cnt, colw, bufB);
    // l3_dot: wave = 4 batch elements (user+item halves)
    const dim3 dotGrid((BATCH_SZ / 4 + 3) / 4);         // 1024 blocks
    gtn_l3_dot_kernel<<<dotGrid, blk, 0, stream>>>(
        bufB, user_emb, item_emb, rowPtr, cnt, colw, users, items, out);
}